// Round 4
// baseline (103.672 us; speedup 1.0000x reference)
//
#include <hip/hip_runtime.h>

// Problem constants (match reference setup_inputs)
#define NBAGS 64
#define D 512              // feature dim (floats)
#define D4 128             // feature dim in float4
#define TARGET_CHUNKS 1024 // 4 blocks per CU on 256 CUs, all co-resident
#define GRID1 1088         // guard headroom if apportionment exceeds 1024

// Shared apportionment (both kernels must agree exactly):
//   n_i = max(1, floor(c_i * TARGET / TT)), then bags 0..L-1 get +1 chunk,
//   where L = TARGET - sum(n_i)  (clamped at 0).
// Bag i's chunk j covers rows [rb + c*j/n, rb + c*(j+1)/n).

// Pass 1: one block per chunk (~128 rows each). block = 256 threads.
// thread t: float4 column (t & 127), row parity (t >> 7).
__global__ void agg_partial_kernel(const float* __restrict__ samples,
                                   const int* __restrict__ counts,
                                   float* __restrict__ partials) {
    const int g = blockIdx.x;   // global chunk id

    // Scan A: total rows.
    long long TT = 0;
#pragma unroll
    for (int i = 0; i < NBAGS; ++i) TT += (long long)counts[i];

    // Scan B: sum of base chunk counts.
    int S = 0;
#pragma unroll
    for (int i = 0; i < NBAGS; ++i) {
        long long c = (long long)counts[i];
        int ni = (int)((c * TARGET_CHUNKS) / TT);
        S += (ni < 1) ? 1 : ni;
    }
    int L = TARGET_CHUNKS - S;
    if (L < 0) L = 0;

    // Scan C: locate the bag owning chunk g.
    int bag = -1, j = 0, n = 1;
    long long rb = 0, c = 0;
    {
        long long cb = 0, rbase = 0;
#pragma unroll
        for (int i = 0; i < NBAGS; ++i) {
            long long ci = (long long)counts[i];
            int ni = (int)((ci * TARGET_CHUNKS) / TT);
            if (ni < 1) ni = 1;
            ni += (i < L) ? 1 : 0;
            if (bag < 0 && g >= cb && g < cb + ni) {
                bag = i; j = (int)(g - cb); rb = rbase; c = ci; n = ni;
            }
            cb += ni; rbase += ci;
        }
    }
    if (bag < 0) return;  // guard blocks beyond total chunk count

    const long long r0 = rb + (c * (long long)j) / n;
    const long long r1 = rb + (c * (long long)(j + 1)) / n;

    const int t    = threadIdx.x;
    const int col  = t & (D4 - 1);
    const int half = t >> 7;

    const float4* __restrict__ src = (const float4*)samples;  // row stride D4

    float4 a0 = make_float4(0.f, 0.f, 0.f, 0.f);
    float4 a1 = make_float4(0.f, 0.f, 0.f, 0.f);
    long long r = r0 + half;
    // 4 loads in flight per thread (rows stride 2 within chunk).
    for (; r + 6 < r1; r += 8) {
        float4 v0 = src[(r    ) * D4 + col];
        float4 v1 = src[(r + 2) * D4 + col];
        float4 v2 = src[(r + 4) * D4 + col];
        float4 v3 = src[(r + 6) * D4 + col];
        a0.x += v0.x; a0.y += v0.y; a0.z += v0.z; a0.w += v0.w;
        a1.x += v1.x; a1.y += v1.y; a1.z += v1.z; a1.w += v1.w;
        a0.x += v2.x; a0.y += v2.y; a0.z += v2.z; a0.w += v2.w;
        a1.x += v3.x; a1.y += v3.y; a1.z += v3.z; a1.w += v3.w;
    }
    for (; r < r1; r += 2) {
        float4 v = src[r * D4 + col];
        a0.x += v.x; a0.y += v.y; a0.z += v.z; a0.w += v.w;
    }
    a0.x += a1.x; a0.y += a1.y; a0.z += a1.z; a0.w += a1.w;

    // Combine the two row-parity halves through LDS; half 0 writes out.
    __shared__ float4 lds[D4];
    if (half == 1) lds[col] = a0;
    __syncthreads();
    if (half == 0) {
        float4 o = lds[col];
        a0.x += o.x; a0.y += o.y; a0.z += o.z; a0.w += o.w;
        ((float4*)partials)[(long long)g * D4 + col] = a0;
    }
}

// Pass 2: one block per bag; reduce its n chunk partials in fixed order,
// scale by 1/count, write out. grid = NBAGS, block = D4.
__global__ void agg_reduce_kernel(const float* __restrict__ partials,
                                  const int* __restrict__ counts,
                                  float* __restrict__ out) {
    const int bag = blockIdx.x;
    const int col = threadIdx.x;  // 0..D4-1

    long long TT = 0;
#pragma unroll
    for (int i = 0; i < NBAGS; ++i) TT += (long long)counts[i];

    int S = 0;
#pragma unroll
    for (int i = 0; i < NBAGS; ++i) {
        long long c = (long long)counts[i];
        int ni = (int)((c * TARGET_CHUNKS) / TT);
        S += (ni < 1) ? 1 : ni;
    }
    int L = TARGET_CHUNKS - S;
    if (L < 0) L = 0;

    long long cb = 0, c = 0;
    int n = 1;
#pragma unroll
    for (int i = 0; i < NBAGS; ++i) {
        long long ci = (long long)counts[i];
        int ni = (int)((ci * TARGET_CHUNKS) / TT);
        if (ni < 1) ni = 1;
        ni += (i < L) ? 1 : 0;
        if (i == bag) { n = ni; c = ci; break; }
        cb += ni;
    }

    const float4* __restrict__ p = (const float4*)partials;
    float4 acc = make_float4(0.f, 0.f, 0.f, 0.f);
    for (int k = 0; k < n; ++k) {
        float4 v = p[(cb + k) * D4 + col];
        acc.x += v.x; acc.y += v.y; acc.z += v.z; acc.w += v.w;
    }
    const float inv = 1.0f / (float)c;
    acc.x *= inv; acc.y *= inv; acc.z *= inv; acc.w *= inv;
    ((float4*)out)[bag * D4 + col] = acc;
}

extern "C" void kernel_launch(void* const* d_in, const int* in_sizes, int n_in,
                              void* d_out, int out_size, void* d_ws, size_t ws_size,
                              hipStream_t stream) {
    const float* samples  = (const float*)d_in[0];
    const int*   counts   = (const int*)d_in[1];   // harness converts int64 -> int32
    float*       out      = (float*)d_out;
    float*       partials = (float*)d_ws;          // GRID1*D floats = 2.2 MiB

    agg_partial_kernel<<<GRID1, 256, 0, stream>>>(samples, counts, partials);
    agg_reduce_kernel<<<NBAGS, D4, 0, stream>>>(partials, counts, out);
}

// Round 5
// 56.213 us; speedup vs baseline: 1.8443x; 1.8443x over previous
//
#include <hip/hip_runtime.h>

// Problem constants (match reference setup_inputs)
#define NBAGS 64
#define D 512              // feature dim (floats)
#define D4 128             // feature dim in float4
#define TARGET_CHUNKS 1024 // 4 blocks per CU on 256 CUs, all co-resident
#define GRID1 1088         // guard headroom (sum of max(1,floor) can exceed 1024)

// Apportionment (identical in both kernels, all 32-bit):
//   n_i = max(1, (c_i * 1024) / TT); L = 1024 - sum(n_i) (clamp 0);
//   bags 0..L-1 get +1. Bag i's chunk j covers [rb + c*j/n, rb + c*(j+1)/n).
// Computed lane-parallel in wave 0 (lane i = bag i), broadcast via LDS.

__device__ __forceinline__ int lane_incl_scan(int v, int lane) {
#pragma unroll
    for (int off = 1; off < 64; off <<= 1) {
        int o = __shfl_up(v, off, 64);
        if (lane >= off) v += o;
    }
    return v;
}

// Pass 1: one block per chunk (~128 rows). block = 256 threads.
// thread t: float4 column (t & 127), row parity (t >> 7).
__global__ __launch_bounds__(256) void
agg_partial_kernel(const float* __restrict__ samples,
                   const int* __restrict__ counts,
                   float* __restrict__ partials, int tt) {
    __shared__ int s_bag, s_r0, s_r1;
    const int t = threadIdx.x;
    const int g = blockIdx.x;

    if (t == 0) s_bag = -1;
    if (t < 64) {  // wave 0, lane t = bag t (lane-0 store above precedes in program order)
        const int c = counts[t];
        int n = (c * TARGET_CHUNKS) / tt;          // 32-bit div, one per lane
        if (n < 1) n = 1;
        int S = n;
#pragma unroll
        for (int m = 1; m < 64; m <<= 1) S += __shfl_xor(S, m, 64);
        int L = TARGET_CHUNKS - S; if (L < 0) L = 0;
        n += (t < L) ? 1 : 0;
        const int cb = lane_incl_scan(n, t) - n;   // chunk base (exclusive)
        const int rb = lane_incl_scan(c, t) - c;   // row base (exclusive)
        if (g >= cb && g < cb + n) {               // exactly one lane matches
            const int j = g - cb;
            s_bag = t;
            s_r0 = rb + (c * j) / n;               // c*j <= ~4.3e6, fits int
            s_r1 = rb + (c * (j + 1)) / n;
        }
    }
    __syncthreads();
    if (s_bag < 0) return;                          // guard block past total chunks
    const int r0 = s_r0, r1 = s_r1;

    const int col  = t & (D4 - 1);
    const int half = t >> 7;

    const float4* __restrict__ src = (const float4*)samples;  // row stride D4

    float4 a0 = make_float4(0.f, 0.f, 0.f, 0.f);
    float4 a1 = make_float4(0.f, 0.f, 0.f, 0.f);
    int r = r0 + half;
    // 4 loads in flight per thread (rows stride 2 within chunk).
    for (; r + 6 < r1; r += 8) {
        float4 v0 = src[(r    ) * D4 + col];
        float4 v1 = src[(r + 2) * D4 + col];
        float4 v2 = src[(r + 4) * D4 + col];
        float4 v3 = src[(r + 6) * D4 + col];
        a0.x += v0.x; a0.y += v0.y; a0.z += v0.z; a0.w += v0.w;
        a1.x += v1.x; a1.y += v1.y; a1.z += v1.z; a1.w += v1.w;
        a0.x += v2.x; a0.y += v2.y; a0.z += v2.z; a0.w += v2.w;
        a1.x += v3.x; a1.y += v3.y; a1.z += v3.z; a1.w += v3.w;
    }
    for (; r < r1; r += 2) {
        float4 v = src[r * D4 + col];
        a0.x += v.x; a0.y += v.y; a0.z += v.z; a0.w += v.w;
    }
    a0.x += a1.x; a0.y += a1.y; a0.z += a1.z; a0.w += a1.w;

    // Combine the two row-parity halves through LDS; half 0 writes out.
    __shared__ float4 lds[D4];
    if (half == 1) lds[col] = a0;
    __syncthreads();
    if (half == 0) {
        float4 o = lds[col];
        a0.x += o.x; a0.y += o.y; a0.z += o.z; a0.w += o.w;
        ((float4*)partials)[g * D4 + col] = a0;
    }
}

// Pass 2: one block per bag; reduce its n chunk partials in fixed order,
// scale by 1/count, write out. grid = NBAGS, block = D4 (128).
__global__ __launch_bounds__(D4) void
agg_reduce_kernel(const float* __restrict__ partials,
                  const int* __restrict__ counts,
                  float* __restrict__ out, int tt) {
    __shared__ int s_cb, s_n;
    const int t   = threadIdx.x;  // 0..127
    const int bag = blockIdx.x;

    if (t < 64) {  // wave 0: same apportionment, lane t = bag t
        const int c = counts[t];
        int n = (c * TARGET_CHUNKS) / tt;
        if (n < 1) n = 1;
        int S = n;
#pragma unroll
        for (int m = 1; m < 64; m <<= 1) S += __shfl_xor(S, m, 64);
        int L = TARGET_CHUNKS - S; if (L < 0) L = 0;
        n += (t < L) ? 1 : 0;
        const int cb = lane_incl_scan(n, t) - n;
        if (t == bag) { s_cb = cb; s_n = n; }
    }
    __syncthreads();
    const int cb = s_cb, n = s_n;

    const float4* __restrict__ p = (const float4*)partials;
    float4 acc = make_float4(0.f, 0.f, 0.f, 0.f);
    for (int k = 0; k < n; ++k) {
        float4 v = p[(cb + k) * D4 + t];
        acc.x += v.x; acc.y += v.y; acc.z += v.z; acc.w += v.w;
    }
    const float inv = 1.0f / (float)counts[bag];
    acc.x *= inv; acc.y *= inv; acc.z *= inv; acc.w *= inv;
    ((float4*)out)[bag * D4 + t] = acc;
}

extern "C" void kernel_launch(void* const* d_in, const int* in_sizes, int n_in,
                              void* d_out, int out_size, void* d_ws, size_t ws_size,
                              hipStream_t stream) {
    const float* samples  = (const float*)d_in[0];
    const int*   counts   = (const int*)d_in[1];   // harness converts int64 -> int32
    float*       out      = (float*)d_out;
    float*       partials = (float*)d_ws;          // GRID1*D floats = 2.2 MiB
    const int    tt       = in_sizes[0] / D;       // total rows (131072)

    agg_partial_kernel<<<GRID1, 256, 0, stream>>>(samples, counts, partials, tt);
    agg_reduce_kernel<<<NBAGS, D4, 0, stream>>>(partials, counts, out, tt);
}